// Round 16
// baseline (316.942 us; speedup 1.0000x reference)
//
#include <hip/hip_runtime.h>

// CCM: causal 3x3 complex multi-frame filter.
// out[b,f,t,:] = sum_{i,j} (Hr+i*Hi)[b,i,j,t,f] * x[b, f+j-1, t+i-2, :]
// H = sum_k c_k * a_k,  c_0 = 1, c_1 = -1/2 + i*sqrt3/2, c_2 = -1/2 - i*sqrt3/2
// a_k = m[b, 9k + 3i + j, t, f]
//
// R16 = R11 skeleton with FLOAT2-PER-LANE m loads (f-pair per thread):
// wave64 m-load covers 512 B (vs 256 B dword) -> half the VMEM requests,
// bigger DRAM bursts. Block = (b, 4-t chunk), 576 threads = 3 k-groups x
// 3 waves; lane l<129 owns f = 2l, 2l+1. Double-buffered 9 x float2 batches.
// c_k folded into window taps; partials of g=1,2 reduced through LDS.
// Boundary lane l=128 (f=256 + invalid 257): scalar m load, second output
// computed on garbage taps and masked at slab/store sinks.

constexpr int B = 8, C = 27, T = 1000, F = 257;
constexpr int TCH = 4;               // t per block tile
constexpr int NT  = T / TCH;         // 250 -> 2000 blocks
constexpr int GRP = 192;             // threads per k-group (3 waves)
constexpr int BLK = 3 * GRP;         // 576
constexpr int NA  = 129;             // active lanes per group (f-pairs)
constexpr int TROW  = TCH + 2;       // staged t range: t0-2 .. t0+3
constexpr int ROWSU = 259;           // rows used: f = -1..257 (row = f+1)
constexpr int RP    = 7;             // odd row pitch -> conflict-free reads
constexpr int PLANE = 260 * RP;      // dwords per x plane
constexpr int RPITCH = 260;          // reduce-slab f pitch (float2 units)

__global__ __launch_bounds__(BLK, 4)   // VGPR cap 128: batches stay live
void ccm_kernel(const float* __restrict__ m,
                const float* __restrict__ x,
                float* __restrict__ out) {
    __shared__ float  xs[2 * PLANE];             // x window: 14.6 KB
    __shared__ float2 rs[2 * TCH * RPITCH];      // partial slabs g=1,2: 16.6 KB

    const int bid = blockIdx.x;
    const int tc  = bid % NT;
    const int b   = bid / NT;
    const int t0  = tc * TCH;
    const int tx  = threadIdx.x;
    const int g   = tx / GRP;          // k-group 0..2 (wave-uniform)
    const int l   = tx - g * GRP;      // lane-in-group (0..191)
    const int c2  = 2 * l;             // first owned f column
    const bool active = (l < NA);

    const float* xb = x + (size_t)b * F * T * 2;

    // ---- stage x window into LDS (re/im planes), all 576 threads ----
    for (int p = tx; p < ROWSU * TROW; p += BLK) {
        const int row = p / TROW;          // 0..258
        const int tt  = p - row * TROW;    // 0..TROW-1
        const int ff  = row - 1;           // -1..257
        const int t   = t0 - 2 + tt;
        float re = 0.f, im = 0.f;
        if (ff >= 0 && ff < F && t >= 0) {
            const float2 v = *reinterpret_cast<const float2*>(
                xb + ((size_t)ff * T + t) * 2);
            re = v.x; im = v.y;
        }
        xs[row * RP + tt]         = re;
        xs[PLANE + row * RP + tt] = im;
    }

    // ---- group constants: c_k ----
    const float SQ3_2 = 0.8660254037844386f;
    const float ckr = (g == 0) ? 1.0f : -0.5f;
    const float cki = (g == 0) ? 0.0f : ((g == 1) ? SQ3_2 : -SQ3_2);

    constexpr size_t CS = (size_t)T * F;   // m channel stride
    const float* mb = m + (((size_t)b * C + 9 * g) * T + t0) * F;

    float2 res[TCH][2];
    float2 Am[9], Bm[9];
    float wr[3][4], wi[3][4];              // 4-wide taps for 2 outputs

// 9 x float2 batch for t-step U (static idx); boundary lane scalar-falls-back
#define LOADM(DST, U)                                                     \
    {                                                                     \
        if (l < NA - 1) {                                                 \
            _Pragma("unroll")                                             \
            for (int n = 0; n < 9; ++n)                                   \
                DST[n] = *reinterpret_cast<const float2*>(                \
                    mb + (size_t)n * CS + (size_t)(U) * F + c2);          \
        } else {                                                          \
            _Pragma("unroll")                                             \
            for (int n = 0; n < 9; ++n)                                   \
                DST[n] = make_float2(                                     \
                    mb[(size_t)n * CS + (size_t)(U) * F + 256], 0.f);     \
        }                                                                 \
    }

// consume batch AV for t-step U: refresh 4 transformed taps, 2x9 complex MACs
#define STEP(AV, U)                                                       \
    {                                                                     \
        _Pragma("unroll")                                                 \
        for (int jj = 0; jj < 4; ++jj) {                                  \
            const float xr = xs[(c2 + jj) * RP + ((U) + 2)];              \
            const float xi = xs[PLANE + (c2 + jj) * RP + ((U) + 2)];      \
            wr[2][jj] = ckr * xr - cki * xi;                              \
            wi[2][jj] = ckr * xi + cki * xr;                              \
        }                                                                 \
        float ar0 = 0.f, ai0 = 0.f, ar1 = 0.f, ai1 = 0.f;                 \
        _Pragma("unroll")                                                 \
        for (int i = 0; i < 3; ++i) {                                     \
            _Pragma("unroll")                                             \
            for (int j = 0; j < 3; ++j) {                                 \
                const int n = i * 3 + j;                                  \
                ar0 += AV[n].x * wr[i][j];                                \
                ai0 += AV[n].x * wi[i][j];                                \
                ar1 += AV[n].y * wr[i][j + 1];                            \
                ai1 += AV[n].y * wi[i][j + 1];                            \
            }                                                             \
        }                                                                 \
        res[U][0] = make_float2(ar0, ai0);                                \
        res[U][1] = make_float2(ar1, ai1);                                \
        _Pragma("unroll")                                                 \
        for (int jj = 0; jj < 4; ++jj) {                                  \
            wr[0][jj] = wr[1][jj]; wi[0][jj] = wi[1][jj];                 \
            wr[1][jj] = wr[2][jj]; wi[1][jj] = wi[2][jj];                 \
        }                                                                 \
    }

    // prologue batches in flight BEFORE the barrier (independent of xs)
    if (active) {
        LOADM(Am, 0);
        LOADM(Bm, 1);
    }
    __syncthreads();

    if (active) {
        // init transformed window rows t0-2, t0-1 (taps f = c2-1 .. c2+2)
        #pragma unroll
        for (int p = 0; p < 2; ++p) {
            #pragma unroll
            for (int jj = 0; jj < 4; ++jj) {
                const float xr = xs[(c2 + jj) * RP + p];
                const float xi = xs[PLANE + (c2 + jj) * RP + p];
                wr[p][jj] = ckr * xr - cki * xi;
                wi[p][jj] = ckr * xi + cki * xr;
            }
        }

        STEP(Am, 0);  LOADM(Am, 2);
        STEP(Bm, 1);  LOADM(Bm, 3);
        STEP(Am, 2);
        STEP(Bm, 3);

        // groups 1,2 deposit partials (260-pitch absorbs the masked f=257)
        if (g > 0) {
            float2* slab = rs + (size_t)(g - 1) * TCH * RPITCH;
            #pragma unroll
            for (int r = 0; r < TCH; ++r) {
                slab[r * RPITCH + c2]     = res[r][0];
                slab[r * RPITCH + c2 + 1] = res[r][1];
            }
        }
    }
#undef LOADM
#undef STEP

    __syncthreads();

    // ---- group 0 reduces and stores 32 B contiguous per owned f row ----
    if (g == 0 && active) {
        const float2* s1 = rs;
        const float2* s2 = rs + (size_t)TCH * RPITCH;
        #pragma unroll
        for (int o = 0; o < 2; ++o) {
            const int fo = c2 + o;
            if (fo < F) {
                float2 acc[TCH];
                #pragma unroll
                for (int r = 0; r < TCH; ++r) {
                    const float2 p1 = s1[r * RPITCH + fo];
                    const float2 p2 = s2[r * RPITCH + fo];
                    acc[r].x = res[r][o].x + p1.x + p2.x;
                    acc[r].y = res[r][o].y + p1.y + p2.y;
                }
                float* op = out + ((size_t)(b * F + fo) * T + t0) * 2;
                #pragma unroll
                for (int u = 0; u < TCH / 2; ++u) {
                    reinterpret_cast<float4*>(op)[u] =
                        make_float4(acc[2 * u].x, acc[2 * u].y,
                                    acc[2 * u + 1].x, acc[2 * u + 1].y);
                }
            }
        }
    }
}

extern "C" void kernel_launch(void* const* d_in, const int* in_sizes, int n_in,
                              void* d_out, int out_size, void* d_ws, size_t ws_size,
                              hipStream_t stream) {
    const float* m = (const float*)d_in[0];
    const float* x = (const float*)d_in[1];
    // d_in[2] = v is a fixed compile-time constant per the reference.
    float* out = (float*)d_out;

    const int grid = B * NT;               // 2000 blocks
    ccm_kernel<<<grid, BLK, 0, stream>>>(m, x, out);
}

// Round 17
// 55.465 us; speedup vs baseline: 5.7143x; 5.7143x over previous
//
#include <hip/hip_runtime.h>

// CCM: causal 3x3 complex multi-frame filter.  [FINAL: R11 champion, 56.3 us]
// out[b,f,t,:] = sum_{i,j} (Hr+i*Hi)[b,i,j,t,f] * x[b, f+j-1, t+i-2, :]
// H = sum_k c_k * a_k,  c_0 = 1, c_1 = -1/2 + i*sqrt3/2, c_2 = -1/2 - i*sqrt3/2
// a_k = m[b, 9k + 3i + j, t, f]
//
// Block = one (b, 4-t chunk), 960 threads = 3 k-groups x 5 waves (lane = f).
// Each group streams its 9 channels as double-buffered 9-load register
// batches, folds c_k into its x-window taps, partials reduced through LDS.
// Session ledger: TCH=8 variants, half-split tiles, raw-barrier prefetch,
// non-temporal x/out, float4/float2-per-lane m loads all flat or negative;
// (960,8) launch bounds clamp VGPR to 32 and spill (R10: 224 MB scratch).

constexpr int B = 8, C = 27, T = 1000, F = 257;
constexpr int TCH = 4;               // t per block tile
constexpr int NT  = T / TCH;         // 250 -> 2000 blocks
constexpr int GRP = 320;             // threads per k-group (5 waves)
constexpr int BLK = 3 * GRP;         // 960
constexpr int TROW  = TCH + 2;       // staged t range: t0-2 .. t0+3
constexpr int ROWSU = 259;           // rows used: f = -1..257 (row = f+1)
constexpr int RP    = 7;             // odd row pitch -> conflict-free reads
constexpr int PLANE = 260 * RP;      // dwords per x plane
constexpr int RPITCH = 260;          // reduce-slab f pitch

__global__ __launch_bounds__(BLK, 4)   // VGPR headroom for live batches
void ccm_kernel(const float* __restrict__ m,
                const float* __restrict__ x,
                float* __restrict__ out) {
    __shared__ float xs[2 * PLANE];              // x window: 14.6 KB
    __shared__ float rs[2 * TCH * RPITCH * 2];   // partial slabs g=1,2: 16.6 KB

    const int bid = blockIdx.x;
    const int tc  = bid % NT;
    const int b   = bid / NT;
    const int t0  = tc * TCH;
    const int tx  = threadIdx.x;
    const int g   = tx / GRP;          // k-group 0..2 (wave-uniform)
    const int f   = tx - g * GRP;      // lane-in-group = f (0..319)
    const bool active = (f < F);

    const float* xb = x + (size_t)b * F * T * 2;

    // ---- stage x window into LDS (re/im planes), all 960 threads ----
    for (int p = tx; p < ROWSU * TROW; p += BLK) {
        const int row = p / TROW;          // 0..258
        const int tt  = p - row * TROW;    // 0..TROW-1
        const int ff  = row - 1;           // -1..257
        const int t   = t0 - 2 + tt;
        float re = 0.f, im = 0.f;
        if (ff >= 0 && ff < F && t >= 0) {
            const float2 v = *reinterpret_cast<const float2*>(
                xb + ((size_t)ff * T + t) * 2);
            re = v.x; im = v.y;
        }
        xs[row * RP + tt]         = re;
        xs[PLANE + row * RP + tt] = im;
    }

    // ---- group constants: c_k ----
    const float SQ3_2 = 0.8660254037844386f;
    const float ckr = (g == 0) ? 1.0f : -0.5f;
    const float cki = (g == 0) ? 0.0f : ((g == 1) ? SQ3_2 : -SQ3_2);

    constexpr size_t CS = (size_t)T * F;   // m channel stride
    const float* mb = m + (((size_t)b * C + 9 * g) * T + t0) * F;

    float2 res[TCH];
    float Am[9], Bm[9];

// 9-load batch for t-step U into named register array DST (static idx)
#define LOADM(DST, U)                                                     \
    {                                                                     \
        _Pragma("unroll")                                                 \
        for (int n = 0; n < 9; ++n)                                       \
            DST[n] = mb[(size_t)n * CS + (size_t)(U) * F + f];            \
    }

// consume batch AV for t-step U: refresh transformed window row 2, 9 MACs
#define STEP(AV, U)                                                       \
    {                                                                     \
        _Pragma("unroll")                                                 \
        for (int j = 0; j < 3; ++j) {                                     \
            const float xr = xs[(f + j) * RP + ((U) + 2)];                \
            const float xi = xs[PLANE + (f + j) * RP + ((U) + 2)];        \
            wr[2][j] = ckr * xr - cki * xi;                               \
            wi[2][j] = ckr * xi + cki * xr;                               \
        }                                                                 \
        float accr = 0.f, acci = 0.f;                                     \
        _Pragma("unroll")                                                 \
        for (int i = 0; i < 3; ++i) {                                     \
            _Pragma("unroll")                                             \
            for (int j = 0; j < 3; ++j) {                                 \
                const int n = i * 3 + j;                                  \
                accr += AV[n] * wr[i][j];                                 \
                acci += AV[n] * wi[i][j];                                 \
            }                                                             \
        }                                                                 \
        res[U] = make_float2(accr, acci);                                 \
        _Pragma("unroll")                                                 \
        for (int j = 0; j < 3; ++j) {                                     \
            wr[0][j] = wr[1][j]; wi[0][j] = wi[1][j];                     \
            wr[1][j] = wr[2][j]; wi[1][j] = wi[2][j];                     \
        }                                                                 \
    }

    // prologue batches in flight BEFORE the barrier (independent of xs)
    if (active) {
        LOADM(Am, 0);
        LOADM(Bm, 1);
    }
    __syncthreads();

    float wr[3][3], wi[3][3];
    if (active) {
        // init transformed window rows t0-2, t0-1
        #pragma unroll
        for (int p = 0; p < 2; ++p) {
            #pragma unroll
            for (int j = 0; j < 3; ++j) {
                const float xr = xs[(f + j) * RP + p];
                const float xi = xs[PLANE + (f + j) * RP + p];
                wr[p][j] = ckr * xr - cki * xi;
                wi[p][j] = ckr * xi + cki * xr;
            }
        }

        STEP(Am, 0);  LOADM(Am, 2);
        STEP(Bm, 1);  LOADM(Bm, 3);
        STEP(Am, 2);
        STEP(Bm, 3);

        // groups 1,2 deposit partials into LDS slabs
        if (g > 0) {
            float2* slab = reinterpret_cast<float2*>(rs) +
                           (size_t)(g - 1) * TCH * RPITCH;
            #pragma unroll
            for (int r = 0; r < TCH; ++r)
                slab[r * RPITCH + f] = res[r];
        }
    }
#undef LOADM
#undef STEP

    __syncthreads();

    // ---- group 0 reduces and stores 32 B/lane contiguous ----
    if (g == 0 && active) {
        const float2* s1 = reinterpret_cast<const float2*>(rs);
        const float2* s2 = s1 + (size_t)TCH * RPITCH;
        #pragma unroll
        for (int r = 0; r < TCH; ++r) {
            const float2 p1 = s1[r * RPITCH + f];
            const float2 p2 = s2[r * RPITCH + f];
            res[r].x += p1.x + p2.x;
            res[r].y += p1.y + p2.y;
        }
        float* op = out + ((size_t)(b * F + f) * T + t0) * 2;
        #pragma unroll
        for (int u = 0; u < TCH / 2; ++u) {
            reinterpret_cast<float4*>(op)[u] =
                make_float4(res[2 * u].x, res[2 * u].y,
                            res[2 * u + 1].x, res[2 * u + 1].y);
        }
    }
}

extern "C" void kernel_launch(void* const* d_in, const int* in_sizes, int n_in,
                              void* d_out, int out_size, void* d_ws, size_t ws_size,
                              hipStream_t stream) {
    const float* m = (const float*)d_in[0];
    const float* x = (const float*)d_in[1];
    // d_in[2] = v is a fixed compile-time constant per the reference.
    float* out = (float*)d_out;

    const int grid = B * NT;               // 2000 blocks
    ccm_kernel<<<grid, BLK, 0, stream>>>(m, x, out);
}